// Round 2
// baseline (1538.945 us; speedup 1.0000x reference)
//
#include <hip/hip_runtime.h>
#include <math.h>

#define NN 50000
#define NE 600000
#define D  128

// ---------------------------------------------------------------------------
// Kernel A: proj = X @ W + b  -> h (d_out), Q, K, V (ws)
// M=50000, N=512, K=128. Tile 64x64, K=128 single shot. 256 threads.
// LDS: A_s[64][128] (XOR-swizzled 16B groups) + B_s[128][64] = 64 KB.
// ---------------------------------------------------------------------------
__global__ __launch_bounds__(256) void node_proj_kernel(
    const float* __restrict__ X,      // [NN][128]
    const float* __restrict__ W,      // [128][512]
    const float* __restrict__ bias,   // [512]
    float* __restrict__ out_h,        // d_out [NN][128]
    float* __restrict__ Qp, float* __restrict__ Kp, float* __restrict__ Vp)
{
    __shared__ float A_s[64 * 128];
    __shared__ float B_s[128 * 64];

    const int tid = threadIdx.x;
    const int bm  = blockIdx.x >> 3;   // 782 row tiles
    const int bn  = blockIdx.x & 7;    // 8 col tiles (x64)
    const int m0  = bm * 64;
    const int n0  = bn * 64;

    // stage A (64x128), swizzle: 16B-group g stored at g ^ (row&31)
#pragma unroll
    for (int i = 0; i < 8; ++i) {
        int j   = tid + i * 256;        // float4 index, 2048 total
        int row = j >> 5;
        int c4  = j & 31;
        float4 v = make_float4(0.f, 0.f, 0.f, 0.f);
        int gr = m0 + row;
        if (gr < NN) v = ((const float4*)(X + (size_t)gr * D))[c4];
        *(float4*)&A_s[row * 128 + ((c4 ^ (row & 31)) << 2)] = v;
    }
    // stage B (128x64)
#pragma unroll
    for (int i = 0; i < 8; ++i) {
        int j   = tid + i * 256;        // 2048 float4
        int row = j >> 4;
        int c4  = j & 15;
        *(float4*)&B_s[row * 64 + (c4 << 2)] =
            ((const float4*)(W + (size_t)row * 512 + n0))[c4];
    }
    __syncthreads();

    const int tx = tid & 15;   // 4 cols each
    const int ty = tid >> 4;   // 4 rows each

    float acc[4][4] = {};
#pragma unroll 4
    for (int k0 = 0; k0 < 128; k0 += 4) {
        float a[4][4], b[4][4];
        const int k4 = k0 >> 2;
#pragma unroll
        for (int i = 0; i < 4; ++i) {
            int row = ty * 4 + i;
            *(float4*)a[i] = *(const float4*)&A_s[row * 128 + ((k4 ^ (row & 31)) << 2)];
        }
#pragma unroll
        for (int j = 0; j < 4; ++j)
            *(float4*)b[j] = *(const float4*)&B_s[(k0 + j) * 64 + (tx << 2)];
#pragma unroll
        for (int i = 0; i < 4; ++i)
#pragma unroll
            for (int j = 0; j < 4; ++j)
#pragma unroll
                for (int c = 0; c < 4; ++c)
                    acc[i][c] += a[i][j] * b[j][c];
    }

    const int sec = bn >> 1;                 // 0:h 1:Q 2:K 3:V
    const int d0  = (bn & 1) * 64 + (tx << 2);
    float* dst = (sec == 0) ? out_h : (sec == 1) ? Qp : (sec == 2) ? Kp : Vp;
    float4 bi = *(const float4*)&bias[n0 + (tx << 2)];
#pragma unroll
    for (int i = 0; i < 4; ++i) {
        int m = m0 + ty * 4 + i;
        if (m < NN) {
            float4 r;
            r.x = acc[i][0] + bi.x;
            r.y = acc[i][1] + bi.y;
            r.z = acc[i][2] + bi.z;
            r.w = acc[i][3] + bi.w;
            *(float4*)&dst[(size_t)m * D + d0] = r;
        }
    }
}

// ---------------------------------------------------------------------------
// Kernel B: per edge  ep = ef @ We + web ; eta = sigmoid(Q[r]+K[s]+ep)
//           atomicAdd(out[r], eta * V[s])
// Block: 64 edges x 64 dims (half of D). 256 threads, 16 out/thread.
// LDS: ef_s[64][128] (swizzled) + We_s[128][64] = 64 KB.
// Grid: 9375 edge-tiles * 2 dim-halves = 18750 blocks.
// ---------------------------------------------------------------------------
__global__ __launch_bounds__(256) void edge_kernel(
    const float* __restrict__ EF,     // [NE][128]
    const int*   __restrict__ snd,
    const int*   __restrict__ rcv,
    const float* __restrict__ We,     // [128][128]
    const float* __restrict__ web,    // [128]
    const float* __restrict__ Qp, const float* __restrict__ Kp,
    const float* __restrict__ Vp,
    float* __restrict__ out)
{
    __shared__ float ef_s[64 * 128];
    __shared__ float We_s[128 * 64];

    const int tid = threadIdx.x;
    const int eb  = blockIdx.x >> 1;          // edge tile
    const int nh  = (blockIdx.x & 1) * 64;    // dim half offset
    const int e0  = eb * 64;

    // stage ef (64x128), swizzled like A_s
#pragma unroll
    for (int i = 0; i < 8; ++i) {
        int j   = tid + i * 256;
        int row = j >> 5;
        int c4  = j & 31;
        float4 v = ((const float4*)(EF + (size_t)(e0 + row) * D))[c4];
        *(float4*)&ef_s[row * 128 + ((c4 ^ (row & 31)) << 2)] = v;
    }
    // stage We half: all 128 k-rows, 64 cols starting at nh
#pragma unroll
    for (int i = 0; i < 8; ++i) {
        int j   = tid + i * 256;        // 2048 float4
        int row = j >> 4;
        int c4  = j & 15;
        *(float4*)&We_s[row * 64 + (c4 << 2)] =
            ((const float4*)(We + (size_t)row * D + nh))[c4];
    }
    __syncthreads();

    const int tx = tid & 15;   // 4 dims each (within 64-dim half)
    const int ty = tid >> 4;   // 4 edges each

    // Hoisted LDS row bases for the a-frag reads (pure ds_read + fmac loop).
    const float* a_base[4];
#pragma unroll
    for (int i = 0; i < 4; ++i) a_base[i] = &ef_s[(ty * 4 + i) * 128];

    float acc[4][4] = {};
#pragma unroll 4
    for (int k0 = 0; k0 < 128; k0 += 4) {
        float a[4][4], b[4][4];
        const int k4 = k0 >> 2;
#pragma unroll
        for (int i = 0; i < 4; ++i) {
            int row = ty * 4 + i;
            *(float4*)a[i] = *(const float4*)&a_base[i][((k4 ^ (row & 31)) << 2)];
        }
#pragma unroll
        for (int j = 0; j < 4; ++j)
            *(float4*)b[j] = *(const float4*)&We_s[(k0 + j) * 64 + (tx << 2)];
#pragma unroll
        for (int i = 0; i < 4; ++i)
#pragma unroll
            for (int j = 0; j < 4; ++j)
#pragma unroll
                for (int c = 0; c < 4; ++c)
                    acc[i][c] += a[i][j] * b[j][c];
    }

    const int d0 = nh + (tx << 2);            // global dim 0..124
    float4 wb = *(const float4*)&web[d0];
#pragma unroll
    for (int i = 0; i < 4; ++i) {
        int e = e0 + ty * 4 + i;
        int s = snd[e];
        int r = rcv[e];
        float4 q  = *(const float4*)&Qp[(size_t)r * D + d0];
        float4 kk = *(const float4*)&Kp[(size_t)s * D + d0];
        float4 v  = *(const float4*)&Vp[(size_t)s * D + d0];
        float x0 = q.x + kk.x + acc[i][0] + wb.x;
        float x1 = q.y + kk.y + acc[i][1] + wb.y;
        float x2 = q.z + kk.z + acc[i][2] + wb.z;
        float x3 = q.w + kk.w + acc[i][3] + wb.w;
        // sigmoid via fast exp (v_exp_f32 path)
        float g0 = 1.f / (1.f + __expf(-x0));
        float g1 = 1.f / (1.f + __expf(-x1));
        float g2 = 1.f / (1.f + __expf(-x2));
        float g3 = 1.f / (1.f + __expf(-x3));
        float* op = out + (size_t)r * D + d0;
        atomicAdd(op + 0, g0 * v.x);
        atomicAdd(op + 1, g1 * v.y);
        atomicAdd(op + 2, g2 * v.z);
        atomicAdd(op + 3, g3 * v.w);
    }
}

extern "C" void kernel_launch(void* const* d_in, const int* in_sizes, int n_in,
                              void* d_out, int out_size, void* d_ws, size_t ws_size,
                              hipStream_t stream)
{
    const float* X   = (const float*)d_in[0];
    const int*   snd = (const int*)  d_in[1];
    const int*   rcv = (const int*)  d_in[2];
    const float* EF  = (const float*)d_in[3];
    const float* W   = (const float*)d_in[4];
    const float* Wb  = (const float*)d_in[5];
    const float* We  = (const float*)d_in[6];
    const float* Web = (const float*)d_in[7];
    float* out = (float*)d_out;

    float* Qp = (float*)d_ws;                       // [NN][128]
    float* Kp = Qp + (size_t)NN * D;                // [NN][128]
    float* Vp = Kp + (size_t)NN * D;                // [NN][128]

    const int gridA = ((NN + 63) / 64) * 8;         // 782 * 8 = 6256
    node_proj_kernel<<<gridA, 256, 0, stream>>>(X, W, Wb, out, Qp, Kp, Vp);

    const int gridB = (NE / 64) * 2;                // 18750
    edge_kernel<<<gridB, 256, 0, stream>>>(EF, snd, rcv, We, Web, Qp, Kp, Vp, out);
}